// Round 8
// baseline (147.059 us; speedup 1.0000x reference)
//
#include <hip/hip_runtime.h>
#include <hip/hip_bf16.h>

// B=16, P=64, De=512, F=128, H=8, hs=64, d_model=512.
// Pipeline:
//   prep:      Bt rows = [Wq|Wv0|Wk0] bf16 transposed, BtO = Wo^T bf16,
//              Wk2t[512][128] = Wk[512:]^T bf16, Wv2bf = Wv[512:] bf16.
//   gemm_qkvu: [1024x1536] = pe(f32, in-reg cvt) @ Bt^T. cols<1024 -> QV,
//              cols>=1024 (K0) -> K0t2[b][d/2][kk][2] transposed bf16.
//   attn:      per (b,q): u[h,f] = sum_d q[hd]*Wk2t[hd][f];
//              s[kk] = q_h.K0t[:,kk] + relf[kk,:].u_h; softmax;
//              AO = attn.V0 + (attn@relf).Wv2
//   gemm_out:  out = AO @ Wo  (f32 out)
// R7 lessons: GEMM register pipelining = null (compiler already covers it);
//             ws fills hide all kernels <43us; ws_size=256MiB.
// R8 changes: (1) relf LDS -> bf16 [64][136], attn LDS 45.5->29.7KB -> 4 blk/CU;
//             (2) drop pe_bf (gemm A-side reads f32 + cvt); (3) XCD-swizzle attn.

typedef __attribute__((ext_vector_type(8))) short short8;
typedef __attribute__((ext_vector_type(4))) short short4v;
typedef __attribute__((ext_vector_type(4))) float f32x4;

static __device__ __forceinline__ short f2bf(float x) {
  __hip_bfloat16 h = __float2bfloat16(x);
  union { __hip_bfloat16 h; short s; } u;
  u.h = h;
  return u.s;
}
static __device__ __forceinline__ float bf2f(short s) {
  union { unsigned int u; float f; } c;
  c.u = ((unsigned int)(unsigned short)s) << 16;
  return c.f;
}
static __device__ __forceinline__ float bflo(unsigned int u) {
  union { unsigned int u; float f; } c; c.u = u << 16; return c.f;
}
static __device__ __forceinline__ float bfhi(unsigned int u) {
  union { unsigned int u; float f; } c; c.u = u & 0xFFFF0000u; return c.f;
}
static __device__ __forceinline__ short8 ldcvt(const float* p) {
  float4 v0 = *(const float4*)p, v1 = *(const float4*)(p + 4);
  short8 r = {f2bf(v0.x), f2bf(v0.y), f2bf(v0.z), f2bf(v0.w),
              f2bf(v1.x), f2bf(v1.y), f2bf(v1.z), f2bf(v1.w)};
  return r;
}

// ---- prep ----
// bid <1024: 32x32 transpose tiles of [Wq|Wv0|Wk0|Wo] -> Bt / BtO
// 1024..1087: Wk2t transpose (Wk[512:640] [128][512] -> [512][128])
// 1088..1151: Wv2bf straight cast (65536 elems)
__global__ __launch_bounds__(256) void prep(const float* __restrict__ Wq,
                                            const float* __restrict__ Wk,
                                            const float* __restrict__ Wv,
                                            const float* __restrict__ Wo,
                                            short* __restrict__ Bt,
                                            short* __restrict__ BtO,
                                            short* __restrict__ Wk2t,
                                            short* __restrict__ Wv2bf) {
  __shared__ float t[32][33];
  const int bid = blockIdx.x, tid = threadIdx.x;
  if (bid < 1024) {
    const int np0 = (bid & 63) * 32, k0 = (bid >> 6) * 32;
    const int tx = tid & 31, ty = tid >> 5;
    const int sid = np0 >> 9;  // 0:Wq 1:Wv0 2:Wk0 3:Wo
    const float* src = (sid == 0) ? Wq : (sid == 1) ? Wv : (sid == 2) ? Wk : Wo;
    const int nc0 = np0 & 511;
#pragma unroll
    for (int r = 0; r < 4; ++r) {
      int kl = ty + r * 8;
      t[kl][tx] = src[(size_t)(k0 + kl) * 512 + nc0 + tx];
    }
    __syncthreads();
#pragma unroll
    for (int r = 0; r < 4; ++r) {
      int nl = ty + r * 8;
      short bv = f2bf(t[tx][nl]);
      int np = np0 + nl;
      if (np < 1536) Bt[(size_t)np * 512 + k0 + tx] = bv;
      else           BtO[(size_t)(np - 1536) * 512 + k0 + tx] = bv;
    }
  } else if (bid < 1088) {
    const int b2 = bid - 1024;
    const int f0 = (b2 & 3) * 32, e0 = (b2 >> 2) * 32;
    const int tx = tid & 31, ty = tid >> 5;
    const float* Wk2 = Wk + 512 * 512;
#pragma unroll
    for (int r = 0; r < 4; ++r) {
      int fl = ty + r * 8;
      t[fl][tx] = Wk2[(size_t)(f0 + fl) * 512 + e0 + tx];
    }
    __syncthreads();
#pragma unroll
    for (int r = 0; r < 4; ++r) {
      int el = ty + r * 8;
      Wk2t[(size_t)(e0 + el) * 128 + f0 + tx] = f2bf(t[tx][el]);
    }
  } else {
    int i = ((bid - 1088) * 256 + tid) * 4;
    const float* Wv2 = Wv + 512 * 512;
    float4 v = *(const float4*)(Wv2 + i);
    short4v o = {f2bf(v.x), f2bf(v.y), f2bf(v.z), f2bf(v.w)};
    *(short4v*)(Wv2bf + i) = o;
  }
}

// ---- big GEMM: [1024 x 1536] = pe(f32) @ Bt^T. cols<1024 -> QV; cols>=1024 -> K0t2 transposed.
__global__ __launch_bounds__(256) void gemm_qkvu(const float* __restrict__ A,
                                                 const short* __restrict__ Bt,
                                                 short* __restrict__ QV,
                                                 short* __restrict__ K0t2) {
  const int wave = threadIdx.x >> 6, lane = threadIdx.x & 63;
  const int wr = wave >> 1, wc = wave & 1;
  const int r = lane & 15, g = lane >> 4;
  const int row0 = blockIdx.x * 64 + wr * 32;
  const int col0 = blockIdx.y * 64 + wc * 32;
  const float* a0f = A + (size_t)(row0 + r) * 512 + g * 8;
  const float* a1f = A + (size_t)(row0 + 16 + r) * 512 + g * 8;
  const short8* b0p = (const short8*)(Bt + (size_t)(col0 + r) * 512 + g * 8);
  const short8* b1p = (const short8*)(Bt + (size_t)(col0 + 16 + r) * 512 + g * 8);
  f32x4 acc00 = {}, acc01 = {}, acc10 = {}, acc11 = {};
  short8 A0[2][4], A1[2][4], B0[2][4], B1[2][4];
  auto LOAD = [&](int buf, int ss) {
#pragma unroll
    for (int c = 0; c < 4; ++c) {
      A0[buf][c] = ldcvt(a0f + (ss * 4 + c) * 32);
      A1[buf][c] = ldcvt(a1f + (ss * 4 + c) * 32);
      B0[buf][c] = b0p[(ss * 4 + c) * 4];
      B1[buf][c] = b1p[(ss * 4 + c) * 4];
    }
  };
  auto MM = [&](int buf) {
#pragma unroll
    for (int c = 0; c < 4; ++c) {
      acc00 = __builtin_amdgcn_mfma_f32_16x16x32_bf16(A0[buf][c], B0[buf][c], acc00, 0, 0, 0);
      acc01 = __builtin_amdgcn_mfma_f32_16x16x32_bf16(A0[buf][c], B1[buf][c], acc01, 0, 0, 0);
      acc10 = __builtin_amdgcn_mfma_f32_16x16x32_bf16(A1[buf][c], B0[buf][c], acc10, 0, 0, 0);
      acc11 = __builtin_amdgcn_mfma_f32_16x16x32_bf16(A1[buf][c], B1[buf][c], acc11, 0, 0, 0);
    }
  };
  LOAD(0, 0);
  LOAD(1, 1);
  MM(0);
  LOAD(0, 2);
  MM(1);
  LOAD(1, 3);
  MM(0);
  MM(1);
  const int crow = (lane >> 4) * 4, ccol = lane & 15;
  const bool k0sec = (blockIdx.y >= 16);
#pragma unroll
  for (int i = 0; i < 2; ++i)
#pragma unroll
    for (int j = 0; j < 2; ++j) {
      f32x4 a = (i == 0) ? (j == 0 ? acc00 : acc01) : (j == 0 ? acc10 : acc11);
#pragma unroll
      for (int rg = 0; rg < 4; ++rg) {
        size_t row = row0 + i * 16 + crow + rg;
        size_t col = col0 + j * 16 + ccol;
        short v = f2bf(a[rg]);
        if (!k0sec) {
          QV[row * 1024 + col] = v;
        } else {
          size_t c = col - 1024;           // 0..511
          size_t b = row >> 6, kk = row & 63;
          K0t2[((b * 256 + (c >> 1)) * 64 + kk) * 2 + (c & 1)] = v;
        }
      }
    }
}

// ---- final GEMM: out[1024x512] f32 = AObf @ BtO^T ----
__global__ __launch_bounds__(256) void gemm_out(const short* __restrict__ A,
                                                const short* __restrict__ Bt,
                                                float* __restrict__ C) {
  const int wave = threadIdx.x >> 6, lane = threadIdx.x & 63;
  const int wr = wave >> 1, wc = wave & 1;
  const int r = lane & 15, g = lane >> 4;
  const int row0 = blockIdx.x * 64 + wr * 32;
  const int col0 = blockIdx.y * 64 + wc * 32;
  const short8* a0p = (const short8*)(A + (size_t)(row0 + r) * 512 + g * 8);
  const short8* a1p = (const short8*)(A + (size_t)(row0 + 16 + r) * 512 + g * 8);
  const short8* b0p = (const short8*)(Bt + (size_t)(col0 + r) * 512 + g * 8);
  const short8* b1p = (const short8*)(Bt + (size_t)(col0 + 16 + r) * 512 + g * 8);
  f32x4 acc00 = {}, acc01 = {}, acc10 = {}, acc11 = {};
  short8 A0[2][4], A1[2][4], B0[2][4], B1[2][4];
  auto LOAD = [&](int buf, int ss) {
#pragma unroll
    for (int c = 0; c < 4; ++c) {
      A0[buf][c] = a0p[(ss * 4 + c) * 4];
      A1[buf][c] = a1p[(ss * 4 + c) * 4];
      B0[buf][c] = b0p[(ss * 4 + c) * 4];
      B1[buf][c] = b1p[(ss * 4 + c) * 4];
    }
  };
  auto MM = [&](int buf) {
#pragma unroll
    for (int c = 0; c < 4; ++c) {
      acc00 = __builtin_amdgcn_mfma_f32_16x16x32_bf16(A0[buf][c], B0[buf][c], acc00, 0, 0, 0);
      acc01 = __builtin_amdgcn_mfma_f32_16x16x32_bf16(A0[buf][c], B1[buf][c], acc01, 0, 0, 0);
      acc10 = __builtin_amdgcn_mfma_f32_16x16x32_bf16(A1[buf][c], B0[buf][c], acc10, 0, 0, 0);
      acc11 = __builtin_amdgcn_mfma_f32_16x16x32_bf16(A1[buf][c], B1[buf][c], acc11, 0, 0, 0);
    }
  };
  LOAD(0, 0);
  LOAD(1, 1);
  MM(0);
  LOAD(0, 2);
  MM(1);
  LOAD(1, 3);
  MM(0);
  MM(1);
  const int crow = (lane >> 4) * 4, ccol = lane & 15;
#pragma unroll
  for (int i = 0; i < 2; ++i)
#pragma unroll
    for (int j = 0; j < 2; ++j) {
      f32x4 a = (i == 0) ? (j == 0 ? acc00 : acc01) : (j == 0 ? acc10 : acc11);
#pragma unroll
      for (int rg = 0; rg < 4; ++rg)
        C[(size_t)(row0 + i * 16 + crow + rg) * 512 + col0 + j * 16 + ccol] = a[rg];
    }
}

// ---- fused attention: one block per (b,q), 8 waves = 1 head each ----
// relf staged as bf16 [64][136] (272B rows, 16B-aligned): LDS 29.7KB -> 4 blocks/CU.
__global__ __launch_bounds__(512) void attn_fused(const short* __restrict__ QV,        // [1024][1024] Q|V0
                                                  const unsigned int* __restrict__ K0t2,  // [16][256][64] uint(2 bf16)
                                                  const float* __restrict__ relf,
                                                  const short* __restrict__ Wk2t,      // [512][128]
                                                  const short* __restrict__ Wv2bf,     // [128][512]
                                                  short* __restrict__ AO) {
  // XCD swizzle: 1024 blocks = 8 XCDs x 128; each XCD gets 2 contiguous b-panels.
  const int orig = blockIdx.x;
  const int bq = (orig & 7) * 128 + (orig >> 3);
  const int b = bq >> 6;
  const int tid = threadIdx.x;
  const int h = tid >> 6, lane = tid & 63;

  __shared__ short relf_s[64][136];  // bf16
  __shared__ float q_s[512];
  __shared__ float u_s[8][128];
  __shared__ float attn_s[8][64];
  __shared__ float w_s[8][128];

  q_s[tid] = bf2f(QV[(size_t)bq * 1024 + tid]);

  // relf[b,q]: 64x128 f32 -> bf16 LDS
  const float* rf = relf + (size_t)bq * 8192;
#pragma unroll
  for (int it = 0; it < 4; ++it) {
    int idx = (it * 512 + tid) * 4;
    float4 gv = *(const float4*)(rf + idx);
    int kk = idx >> 7, f = idx & 127;
    short4v o = {f2bf(gv.x), f2bf(gv.y), f2bf(gv.z), f2bf(gv.w)};
    *(short4v*)&relf_s[kk][f] = o;
  }
  __syncthreads();  // only block-wide barrier

  // u[h][f] for f = 2*lane, 2*lane+1: coalesced uint rows of Wk2t
  {
    const unsigned int* wp = (const unsigned int*)(Wk2t + (size_t)h * 64 * 128) + lane;
    float u0 = 0.f, u1 = 0.f;
#pragma unroll 8
    for (int d = 0; d < 64; ++d) {
      unsigned int uv = wp[d * 64];
      float qd = q_s[h * 64 + d];
      u0 += qd * bflo(uv);
      u1 += qd * bfhi(uv);
    }
    u_s[h][lane * 2] = u0;
    u_s[h][lane * 2 + 1] = u1;
  }

  // scores: lane = kk
  float s = 0.f;
  {
    const unsigned int* kp = K0t2 + ((size_t)b * 256 + h * 32) * 64 + lane;
#pragma unroll 8
    for (int d2 = 0; d2 < 32; ++d2) {
      unsigned int uv = kp[(size_t)d2 * 64];
      s += q_s[h * 64 + d2 * 2] * bflo(uv) + q_s[h * 64 + d2 * 2 + 1] * bfhi(uv);
    }
#pragma unroll
    for (int f8 = 0; f8 < 16; ++f8) {
      short8 rv = *(const short8*)&relf_s[lane][f8 * 8];
      float4 ua = *(const float4*)&u_s[h][f8 * 8];
      float4 ub = *(const float4*)&u_s[h][f8 * 8 + 4];
      s += ua.x * bf2f(rv[0]) + ua.y * bf2f(rv[1]) + ua.z * bf2f(rv[2]) + ua.w * bf2f(rv[3]);
      s += ub.x * bf2f(rv[4]) + ub.y * bf2f(rv[5]) + ub.z * bf2f(rv[6]) + ub.w * bf2f(rv[7]);
    }
    s *= 0.125f;
  }
  // 64-lane softmax
  float m = s;
#pragma unroll
  for (int off = 32; off; off >>= 1) m = fmaxf(m, __shfl_xor(m, off));
  float p = __expf(s - m);
  float sum = p;
#pragma unroll
  for (int off = 32; off; off >>= 1) sum += __shfl_xor(sum, off);
  attn_s[h][lane] = p / sum;

  // w[f] = attn . relf[:,f], f = lane, lane+64 (intra-wave, no barrier)
  {
    float w0 = 0.f, w1 = 0.f;
#pragma unroll 8
    for (int kk = 0; kk < 64; ++kk) {
      float a = attn_s[h][kk];
      w0 += a * bf2f(relf_s[kk][lane]);
      w1 += a * bf2f(relf_s[kk][lane + 64]);
    }
    w_s[h][lane] = w0;
    w_s[h][lane + 64] = w1;
  }

  // out: lane = d
  float o = 0.f;
  {
    const short* v0col = QV + (size_t)(b * 64) * 1024 + 512 + h * 64 + lane;
#pragma unroll 16
    for (int kk = 0; kk < 64; ++kk) o += attn_s[h][kk] * bf2f(v0col[(size_t)kk * 1024]);
    const short* wvcol = Wv2bf + h * 64 + lane;
#pragma unroll 16
    for (int f = 0; f < 128; ++f) o += w_s[h][f] * bf2f(wvcol[(size_t)f * 512]);
  }
  AO[(size_t)bq * 512 + h * 64 + lane] = f2bf(o);
}

extern "C" void kernel_launch(void* const* d_in, const int* in_sizes, int n_in,
                              void* d_out, int out_size, void* d_ws, size_t ws_size,
                              hipStream_t stream) {
  const float* pe   = (const float*)d_in[0];  // [16,64,512]
  const float* relf = (const float*)d_in[1];  // [16,64,64,128]
  const float* Wq = (const float*)d_in[3];    // [512,512]
  const float* Wk = (const float*)d_in[4];    // [640,512]
  const float* Wv = (const float*)d_in[5];    // [640,512]
  const float* Wo = (const float*)d_in[6];    // [512,512]
  float* out = (float*)d_out;                 // [16,64,512] f32

  short* ws = (short*)d_ws;
  short* Bt    = ws;                    // 786432 shorts (1.5 MB)
  short* BtO   = Bt + 786432;           // 262144 (0.5 MB)
  short* Wk2t  = BtO + 262144;          // 65536 (128 KB)
  short* Wv2bf = Wk2t + 65536;          // 65536 (128 KB)
  short* QV    = Wv2bf + 65536;         // 1048576 (2 MB)
  short* K0t2  = QV + 1048576;          // 524288 (1 MB)
  short* AObf  = K0t2 + 524288;         // 524288 (1 MB)  -> total ~6.2 MB

  prep<<<1152, 256, 0, stream>>>(Wq, Wk, Wv, Wo, Bt, BtO, Wk2t, Wv2bf);
  gemm_qkvu<<<dim3(16, 24), 256, 0, stream>>>(pe, Bt, QV, K0t2);
  attn_fused<<<1024, 512, 0, stream>>>(QV, (const unsigned int*)K0t2, relf, Wk2t, Wv2bf, AObf);
  gemm_out<<<dim3(16, 8), 256, 0, stream>>>(AObf, BtO, out);
}